// Round 4
// baseline (616.005 us; speedup 1.0000x reference)
//
#include <hip/hip_runtime.h>

#pragma clang fp contract(off)

#define BATCH 16
#define NPTS  4096
#define KNN   32
#define NW    4                 // waves per block = candidate-chunk split factor
#define CHUNK (NPTS / NW)       // 1024 candidates per wave
#define CH    30
#define FDEPTH 32               // per-lane index-FIFO depth (provably sufficient)

#define INF_F __builtin_inff()

// Order-preserving float->uint encoding for atomic max (handles negatives).
__device__ __forceinline__ unsigned enc_f32(float f) {
    unsigned u = __float_as_uint(f);
    return (u & 0x80000000u) ? ~u : (u | 0x80000000u);
}
__device__ __forceinline__ float dec_f32(unsigned e) {
    unsigned u = (e & 0x80000000u) ? (e & 0x7FFFFFFFu) : ~e;
    return __uint_as_float(u);
}

__device__ __forceinline__ float med3f(float a, float b, float c) {
#if __has_builtin(__builtin_amdgcn_fmed3f)
    return __builtin_amdgcn_fmed3f(a, b, c);
#else
    float r;
    asm("v_med3_f32 %0, %1, %2, %3" : "=v"(r) : "v"(a), "v"(b), "v"(c));
    return r;
#endif
}

__global__ void init_pool_kernel(unsigned* __restrict__ pool) {
    int i = blockIdx.x * blockDim.x + threadIdx.x;
    if (i < BATCH * CH) pool[i] = 0u;   // 0 is below every encoded finite float
}

// Block: 256 threads = 4 waves. Lane l owns query (qg*64 + l); wave w scans
// candidate chunk [w*1024, w*1024+1024) from LDS-staged SoA planes.
__launch_bounds__(256, 2)
__global__ void knn_feat_kernel(const float* __restrict__ x,
                                unsigned* __restrict__ pool) {
    extern __shared__ float smem[];
    float* __restrict__ psx = smem;                 // [NPTS] 16 KB
    float* __restrict__ psy = smem + NPTS;          // [NPTS] 16 KB
    float* __restrict__ psz = smem + 2 * NPTS;      // [NPTS] 16 KB
    float* __restrict__ buf = smem + 3 * NPTS;      // 32 KB: lists, then FIFO+partials

    const int b   = blockIdx.x >> 6;                // 64 query-groups per batch
    const int qg  = blockIdx.x & 63;
    const int tid = threadIdx.x;
    const int w   = tid >> 6;                       // wave id = chunk id
    const int l   = tid & 63;                       // lane = query slot
    const int q   = qg * 64 + l;
    const float* __restrict__ xb = x + (size_t)b * NPTS * 3;

    // Stage the whole batch as 3 SoA planes.
    for (int pt = tid; pt < NPTS; pt += 256) {
        psx[pt] = xb[pt * 3 + 0];
        psy[pt] = xb[pt * 3 + 1];
        psz[pt] = xb[pt * 3 + 2];
    }
    __syncthreads();

    const float qx = psx[q], qy = psy[q], qz = psz[q];
    const float qw = qx * qx + qy * qy + qz * qz;

    // ---- Pass 1: top-32 distance VALUES of my chunk (sorted asc). ----
    float arr[KNN];
#pragma unroll
    for (int j = 0; j < KNN; ++j) arr[j] = INF_F;

    const int base = w * CHUNK;
    for (int m = 0; m < CHUNK; ++m) {
        float px = psx[base + m], py = psy[base + m], pz = psz[base + m];
        float pw  = px * px + py * py + pz * pz;   // bit-identical everywhere
        float dot = qx * px + qy * py + qz * pz;
        float d   = qw + pw - 2.0f * dot;
#pragma unroll
        for (int j = KNN - 1; j >= 1; --j)
            arr[j] = med3f(arr[j - 1], arr[j], d);  // reads OLD arr[j-1]
        arr[0] = fminf(arr[0], d);
    }

#pragma unroll
    for (int j = 0; j < KNN; ++j) buf[(w * KNN + j) * 64 + l] = arr[j];
    __syncthreads();

    // ---- Merge the 4 sorted lists for query l (done redundantly per wave):
    // thr = 32nd smallest of the union == global 32nd smallest distance.
    float thr;
    {
        float v0 = buf[(0 * KNN) * 64 + l];
        float v1 = buf[(1 * KNN) * 64 + l];
        float v2 = buf[(2 * KNN) * 64 + l];
        float v3 = buf[(3 * KNN) * 64 + l];
        int h0 = 1, h1 = 1, h2 = 1, h3 = 1;
        float mv = 0.f;
#pragma unroll 1
        for (int it = 0; it < KNN; ++it) {
            mv = fminf(fminf(v0, v1), fminf(v2, v3));
            if (it == KNN - 1) break;
            if (v0 == mv)      { v0 = (h0 < KNN) ? buf[(0 * KNN + h0) * 64 + l] : INF_F; ++h0; }
            else if (v1 == mv) { v1 = (h1 < KNN) ? buf[(1 * KNN + h1) * 64 + l] : INF_F; ++h1; }
            else if (v2 == mv) { v2 = (h2 < KNN) ? buf[(2 * KNN + h2) * 64 + l] : INF_F; ++h2; }
            else               { v3 = (h3 < KNN) ? buf[(3 * KNN + h3) * 64 + l] : INF_F; ++h3; }
        }
        thr = mv;
    }

    // Counts per chunk: everything < thr is provably inside its chunk's top-32.
    int lt0 = 0, lt1 = 0, lt2 = 0, lt3 = 0;
    int eq0 = 0, eq1 = 0, eq2 = 0;
#pragma unroll
    for (int j = 0; j < KNN; ++j) {
        float a0 = buf[(0 * KNN + j) * 64 + l]; lt0 += a0 < thr; eq0 += a0 == thr;
        float a1 = buf[(1 * KNN + j) * 64 + l]; lt1 += a1 < thr; eq1 += a1 == thr;
        float a2 = buf[(2 * KNN + j) * 64 + l]; lt2 += a2 < thr; eq2 += a2 == thr;
        float a3 = buf[(3 * KNN + j) * 64 + l]; lt3 += a3 < thr;
    }
    const int need = KNN - (lt0 + lt1 + lt2 + lt3);   // ties to take globally
    int before;
    if (w == 0)      before = 0;
    else if (w == 1) before = eq0;
    else if (w == 2) before = eq0 + eq1;
    else             before = eq0 + eq1 + eq2;
    int quota = need - before;
    if (quota < 0) quota = 0;                          // ties taken in index order

    __syncthreads();   // all list reads done; buf is reused as index-FIFO

    // ---- Pass 2a: collect indices of candidates with d <= thr. ----
    // FIFO layout [w][i][lane] (u32 view): lane-contiguous, conflict-free.
    unsigned* __restrict__ fb = (unsigned*)buf;
    int cnt = 0;
    for (int m = 0; m < CHUNK; ++m) {
        float px = psx[base + m], py = psy[base + m], pz = psz[base + m];
        float pw  = px * px + py * py + pz * pz;
        float dot = qx * px + qy * py + qz * pz;
        float d   = qw + pw - 2.0f * dot;              // bit-identical to pass 1
        if (__any(d <= thr)) {                         // skips ~58% of candidates
            if (d <= thr && cnt < FDEPTH) {
                fb[((w * FDEPTH + cnt) * 64) + l] = (unsigned)m;
                ++cnt;
            }
        }
    }

    // ---- Pass 2b: stats over my <=32 collected entries. ----
    float s0 = 0.f, s1 = 0.f, s2 = 0.f;
    float ss0 = 0.f, ss1 = 0.f, ss2 = 0.f;
    float mx0 = -INF_F, mx1 = -INF_F, mx2 = -INF_F;
    float mn0 =  INF_F, mn1 =  INF_F, mn2 =  INF_F;
    int maxcnt = cnt;
#pragma unroll
    for (int off = 32; off >= 1; off >>= 1) {
        int o = __shfl_xor(maxcnt, off, 64);
        maxcnt = (o > maxcnt) ? o : maxcnt;
    }
    int eq_seen = 0;
    for (int i = 0; i < maxcnt; ++i) {
        bool act = (i < cnt);
        unsigned mr = fb[((w * FDEPTH + i) * 64) + l];  // addr always in-bounds
        int m = act ? (int)mr : 0;                       // gate garbage values
        float px = psx[base + m], py = psy[base + m], pz = psz[base + m];
        float pw  = px * px + py * py + pz * pz;
        float dot = qx * px + qy * py + qz * pz;
        float d   = qw + pw - 2.0f * dot;                // bit-identical again
        bool is_eq = (d == thr);
        bool take = act && ((d < thr) || (is_eq && eq_seen < quota));
        eq_seen += (act && is_eq) ? 1 : 0;
        if (take) {
            float r0 = px - qx, r1 = py - qy, r2 = pz - qz;
            s0 += r0;  s1 += r1;  s2 += r2;
            ss0 += r0 * r0;  ss1 += r1 * r1;  ss2 += r2 * r2;
            mx0 = fmaxf(mx0, r0); mx1 = fmaxf(mx1, r1); mx2 = fmaxf(mx2, r2);
            mn0 = fminf(mn0, r0); mn1 = fminf(mn1, r1); mn2 = fminf(mn2, r2);
        }
    }

    // Stash partial stats into THIS wave's own (fully consumed) FIFO region.
    // Slot (w,c,l) = buf[w*2048 + c*64 + l], c < 12 < 2048/64.
    {
        float* pr = buf + w * (FDEPTH * 64);
        pr[ 0 * 64 + l] = s0;   pr[ 1 * 64 + l] = s1;
        pr[ 2 * 64 + l] = s2;   pr[ 3 * 64 + l] = ss0;
        pr[ 4 * 64 + l] = ss1;  pr[ 5 * 64 + l] = ss2;
        pr[ 6 * 64 + l] = mx0;  pr[ 7 * 64 + l] = mx1;
        pr[ 8 * 64 + l] = mx2;  pr[ 9 * 64 + l] = mn0;
        pr[10 * 64 + l] = mn1;  pr[11 * 64 + l] = mn2;
    }
    __syncthreads();

    if (w != 0) return;   // no barriers past this point

    // ---- Combine 4 partials, build 30 channels, wave-max, one atomic. ----
#define RD(ww, c) buf[(ww) * (FDEPTH * 64) + (c) * 64 + l]
    s0  = RD(0,0) + RD(1,0) + RD(2,0) + RD(3,0);
    s1  = RD(0,1) + RD(1,1) + RD(2,1) + RD(3,1);
    s2  = RD(0,2) + RD(1,2) + RD(2,2) + RD(3,2);
    ss0 = RD(0,3) + RD(1,3) + RD(2,3) + RD(3,3);
    ss1 = RD(0,4) + RD(1,4) + RD(2,4) + RD(3,4);
    ss2 = RD(0,5) + RD(1,5) + RD(2,5) + RD(3,5);
    mx0 = fmaxf(fmaxf(RD(0,6), RD(1,6)), fmaxf(RD(2,6), RD(3,6)));
    mx1 = fmaxf(fmaxf(RD(0,7), RD(1,7)), fmaxf(RD(2,7), RD(3,7)));
    mx2 = fmaxf(fmaxf(RD(0,8), RD(1,8)), fmaxf(RD(2,8), RD(3,8)));
    mn0 = fminf(fminf(RD(0,9), RD(1,9)), fminf(RD(2,9), RD(3,9)));
    mn1 = fminf(fminf(RD(0,10), RD(1,10)), fminf(RD(2,10), RD(3,10)));
    mn2 = fminf(fminf(RD(0,11), RD(1,11)), fminf(RD(2,11), RD(3,11)));
#undef RD

    const float invk = 1.0f / (float)KNN;
    float mu0 = s0 * invk, mu1 = s1 * invk, mu2 = s2 * invk;
    float ex0 = ss0 * invk, ex1 = ss1 * invk, ex2 = ss2 * invk;
    float st0 = sqrtf(fmaxf(ex0 - mu0 * mu0, 0.f));
    float st1 = sqrtf(fmaxf(ex1 - mu1 * mu1, 0.f));
    float st2 = sqrtf(fmaxf(ex2 - mu2 * mu2, 0.f));
    float nrm = sqrtf(mu0 * mu0 + mu1 * mu1 + mu2 * mu2) + 1e-8f;
    float u0 = mu0 / nrm, u1 = mu1 / nrm, u2 = mu2 / nrm;
    float cr0 = qy * u2 - qz * u1;
    float cr1 = qz * u0 - qx * u2;
    float cr2 = qx * u1 - qy * u0;
    float mq0 = fmaxf(mx0 * mx0, mn0 * mn0);
    float mq1 = fmaxf(mx1 * mx1, mn1 * mn1);
    float mq2 = fmaxf(mx2 * mx2, mn2 * mn2);

    float f[CH] = { qx, qy, qz,
                    mu0, mu1, mu2,
                    mx0, mx1, mx2,
                    mn0, mn1, mn2,
                    st0, st1, st2,
                    qx - mu0, qy - mu1, qz - mu2,
                    u0, u1, u2,
                    cr0, cr1, cr2,
                    mq0, mq1, mq2,
                    ex0, ex1, ex2 };

#pragma unroll
    for (int c = 0; c < CH; ++c) {
        float v = f[c];
#pragma unroll
        for (int off = 32; off >= 1; off >>= 1)
            v = fmaxf(v, __shfl_xor(v, off, 64));
        if (l == 0)
            atomicMax(pool + b * CH + c, enc_f32(v));
    }
}

__global__ void final_mm_kernel(const unsigned* __restrict__ pool,
                                const float* __restrict__ W,
                                const float* __restrict__ bias,
                                float* __restrict__ out) {
    int t = blockIdx.x * blockDim.x + threadIdx.x;
    if (t >= BATCH * 32) return;
    int bb = t >> 5, e = t & 31;
    float acc = bias[e];
#pragma unroll
    for (int c = 0; c < CH; ++c)
        acc += dec_f32(pool[bb * CH + c]) * W[e * CH + c];
    out[bb * 32 + e] = acc;
}

extern "C" void kernel_launch(void* const* d_in, const int* in_sizes, int n_in,
                              void* d_out, int out_size, void* d_ws, size_t ws_size,
                              hipStream_t stream) {
    const float* x    = (const float*)d_in[0];   // [16, 4096, 3] f32
    const float* W    = (const float*)d_in[1];   // [32, 30] f32
    const float* bias = (const float*)d_in[2];   // [32] f32
    float*       out  = (float*)d_out;           // [16, 32] f32
    unsigned*    pool = (unsigned*)d_ws;         // [16, 30] encoded f32

    const size_t lds_bytes = (size_t)(3 * NPTS + NW * KNN * 64) * sizeof(float); // 80 KB

    hipLaunchKernelGGL(init_pool_kernel, dim3(1), dim3(512), 0, stream, pool);
    hipLaunchKernelGGL(knn_feat_kernel, dim3(BATCH * (NPTS / 64)), dim3(256),
                       lds_bytes, stream, x, pool);
    hipLaunchKernelGGL(final_mm_kernel, dim3(1), dim3(512), 0, stream, pool, W, bias, out);
}

// Round 5
// 311.036 us; speedup vs baseline: 1.9805x; 1.9805x over previous
//
#include <hip/hip_runtime.h>

#pragma clang fp contract(off)

#define BATCH 16
#define NPTS  4096
#define KNN   32
#define NW    4                 // waves per block = candidate-chunk split factor
#define CHUNK (NPTS / NW)       // 1024 candidates per wave
#define CH    30
#define Q8    8                 // per-chunk list depth (union 4*8 = 32 -> t_cap bound)
#define FD    56                // per-(wave,lane) index-FIFO depth (u16 entries)

#define INF_F __builtin_inff()

// Order-preserving float->uint encoding for atomic max (handles negatives).
__device__ __forceinline__ unsigned enc_f32(float f) {
    unsigned u = __float_as_uint(f);
    return (u & 0x80000000u) ? ~u : (u | 0x80000000u);
}
__device__ __forceinline__ float dec_f32(unsigned e) {
    unsigned u = (e & 0x80000000u) ? (e & 0x7FFFFFFFu) : ~e;
    return __uint_as_float(u);
}

__device__ __forceinline__ float med3f(float a, float b, float c) {
#if __has_builtin(__builtin_amdgcn_fmed3f)
    return __builtin_amdgcn_fmed3f(a, b, c);
#else
    float r;
    asm("v_med3_f32 %0, %1, %2, %3" : "=v"(r) : "v"(a), "v"(b), "v"(c));
    return r;
#endif
}

// One fixed fma-form distance used in EVERY pass -> bit-identical everywhere.
__device__ __forceinline__ float dist3(float qx, float qy, float qz, float qw,
                                       float px, float py, float pz) {
    float pw = __builtin_fmaf(px, px, __builtin_fmaf(py, py, pz * pz));
    float dt = __builtin_fmaf(qx, px, __builtin_fmaf(qy, py, qz * pz));
    return __builtin_fmaf(-2.0f, dt, qw + pw);
}

__global__ void init_pool_kernel(unsigned* __restrict__ pool) {
    int i = blockIdx.x * blockDim.x + threadIdx.x;
    if (i < BATCH * CH) pool[i] = 0u;   // 0 is below every encoded finite float
}

// Block: 256 threads = 4 waves. Lane l owns query (qg*64 + l); wave w scans
// candidate chunk [w*1024, w*1024+1024) from LDS-staged SoA planes.
// Phase 1: per-chunk top-8 -> t_cap (provable bound on the 32nd distance).
// Phase 2: collect indices with d <= t_cap (u16 FIFO).
// Phase 3 (wave 0): exact top-32 + tie quota + stats over ~45 survivors.
__launch_bounds__(256, 2)
__global__ void knn_feat_kernel(const float* __restrict__ x,
                                unsigned* __restrict__ pool) {
    extern __shared__ float smem[];
    float* __restrict__ psx = smem;                  // [4096] 16 KB
    float* __restrict__ psy = smem + NPTS;           // [4096] 16 KB
    float* __restrict__ psz = smem + 2 * NPTS;       // [4096] 16 KB
    float* __restrict__ t8  = smem + 3 * NPTS;       // [NW*64] arr[7] stash, 1 KB
    int*   __restrict__ cb  = (int*)(smem + 3 * NPTS + NW * 64);       // [NW*64] 1 KB
    unsigned short* __restrict__ fifo =
        (unsigned short*)(smem + 3 * NPTS + 2 * NW * 64);  // [NW*FD*64] u16, 28 KB

    const int b   = blockIdx.x >> 6;                 // 64 query-groups per batch
    const int qg  = blockIdx.x & 63;
    const int tid = threadIdx.x;
    const int w   = tid >> 6;                        // wave id = chunk id
    const int l   = tid & 63;                        // lane = query slot
    const int q   = qg * 64 + l;
    const float* __restrict__ xb = x + (size_t)b * NPTS * 3;

    // Stage the whole batch as 3 SoA planes.
    for (int pt = tid; pt < NPTS; pt += 256) {
        psx[pt] = xb[pt * 3 + 0];
        psy[pt] = xb[pt * 3 + 1];
        psz[pt] = xb[pt * 3 + 2];
    }
    __syncthreads();

    const float qx = psx[q], qy = psy[q], qz = psz[q];
    const float qw = __builtin_fmaf(qx, qx, __builtin_fmaf(qy, qy, qz * qz));

    const int base = w * CHUNK;
    const float4* __restrict__ px4 = (const float4*)(psx + base);
    const float4* __restrict__ py4 = (const float4*)(psy + base);
    const float4* __restrict__ pz4 = (const float4*)(psz + base);

    // ---- Pass 1: top-8 distance VALUES of my chunk (sorted asc). ----
    float arr[Q8];
#pragma unroll
    for (int j = 0; j < Q8; ++j) arr[j] = INF_F;

#define INSERT8(dv)                                            \
    {                                                          \
        _Pragma("unroll")                                      \
        for (int j = Q8 - 1; j >= 1; --j)                      \
            arr[j] = med3f(arr[j - 1], arr[j], (dv));          \
        arr[0] = fminf(arr[0], (dv));                          \
    }

    for (int m4 = 0; m4 < CHUNK / 4; ++m4) {
        float4 X = px4[m4], Y = py4[m4], Z = pz4[m4];   // uniform-addr broadcast
        float d0 = dist3(qx, qy, qz, qw, X.x, Y.x, Z.x);
        float d1 = dist3(qx, qy, qz, qw, X.y, Y.y, Z.y);
        float d2 = dist3(qx, qy, qz, qw, X.z, Y.z, Z.z);
        float d3 = dist3(qx, qy, qz, qw, X.w, Y.w, Z.w);
        INSERT8(d0); INSERT8(d1); INSERT8(d2); INSERT8(d3);
    }
#undef INSERT8

    t8[w * 64 + l] = arr[Q8 - 1];
    __syncthreads();

    // t_cap >= true 32nd distance: union of 4 chunk-top-8s = 32 distinct points.
    const float t_cap = fmaxf(fmaxf(t8[0 * 64 + l], t8[1 * 64 + l]),
                              fmaxf(t8[2 * 64 + l], t8[3 * 64 + l]));

    // ---- Pass 2: collect chunk-local indices with d <= t_cap. ----
    unsigned short* __restrict__ fw = fifo + (w * FD) * 64 + l;
    int cnt = 0;
    for (int m4 = 0; m4 < CHUNK / 4; ++m4) {
        float4 X = px4[m4], Y = py4[m4], Z = pz4[m4];
        float d0 = dist3(qx, qy, qz, qw, X.x, Y.x, Z.x);
        float d1 = dist3(qx, qy, qz, qw, X.y, Y.y, Z.y);
        float d2 = dist3(qx, qy, qz, qw, X.z, Y.z, Z.z);
        float d3 = dist3(qx, qy, qz, qw, X.w, Y.w, Z.w);
        int mb = m4 * 4;
        if (d0 <= t_cap && cnt < FD) { fw[cnt * 64] = (unsigned short)(mb + 0); ++cnt; }
        if (d1 <= t_cap && cnt < FD) { fw[cnt * 64] = (unsigned short)(mb + 1); ++cnt; }
        if (d2 <= t_cap && cnt < FD) { fw[cnt * 64] = (unsigned short)(mb + 2); ++cnt; }
        if (d3 <= t_cap && cnt < FD) { fw[cnt * 64] = (unsigned short)(mb + 3); ++cnt; }
    }
    cb[w * 64 + l] = cnt;
    __syncthreads();

    if (w != 0) return;   // no barriers past this point

    // ---- Phase 3 (wave 0): exact selection + stats over collected entries. ----
    const int c0 = cb[0 * 64 + l], c1 = cb[1 * 64 + l],
              c2 = cb[2 * 64 + l], c3 = cb[3 * 64 + l];

    float a32[KNN];
#pragma unroll
    for (int j = 0; j < KNN; ++j) a32[j] = INF_F;

#pragma unroll
    for (int ww = 0; ww < NW; ++ww) {
        const int c = (ww == 0) ? c0 : (ww == 1) ? c1 : (ww == 2) ? c2 : c3;
        for (int i = 0; i < c; ++i) {
            int idx = (int)fifo[((ww * FD + i) * 64) + l] + ww * CHUNK;
            float d = dist3(qx, qy, qz, qw, psx[idx], psy[idx], psz[idx]);
#pragma unroll
            for (int j = KNN - 1; j >= 1; --j)
                a32[j] = med3f(a32[j - 1], a32[j], d);
            a32[0] = fminf(a32[0], d);
        }
    }
    const float thr = a32[KNN - 1];
    int c_lt = 0;
#pragma unroll
    for (int j = 0; j < KNN; ++j) c_lt += a32[j] < thr;
    const int need = KNN - c_lt;                   // ties to take, in index order

    float s0 = 0.f, s1 = 0.f, s2 = 0.f;
    float ss0 = 0.f, ss1 = 0.f, ss2 = 0.f;
    float mx0 = -INF_F, mx1 = -INF_F, mx2 = -INF_F;
    float mn0 =  INF_F, mn1 =  INF_F, mn2 =  INF_F;
    int eq_seen = 0;
#pragma unroll
    for (int ww = 0; ww < NW; ++ww) {              // (ww asc, i asc) = index order
        const int c = (ww == 0) ? c0 : (ww == 1) ? c1 : (ww == 2) ? c2 : c3;
        for (int i = 0; i < c; ++i) {
            int idx = (int)fifo[((ww * FD + i) * 64) + l] + ww * CHUNK;
            float px = psx[idx], py = psy[idx], pz = psz[idx];
            float d = dist3(qx, qy, qz, qw, px, py, pz);
            bool is_eq = (d == thr);
            bool take = (d < thr) || (is_eq && eq_seen < need);
            eq_seen += is_eq ? 1 : 0;
            if (take) {
                float r0 = px - qx, r1 = py - qy, r2 = pz - qz;
                s0 += r0;  s1 += r1;  s2 += r2;
                ss0 += r0 * r0;  ss1 += r1 * r1;  ss2 += r2 * r2;
                mx0 = fmaxf(mx0, r0); mx1 = fmaxf(mx1, r1); mx2 = fmaxf(mx2, r2);
                mn0 = fminf(mn0, r0); mn1 = fminf(mn1, r1); mn2 = fminf(mn2, r2);
            }
        }
    }

    const float invk = 1.0f / (float)KNN;
    float mu0 = s0 * invk, mu1 = s1 * invk, mu2 = s2 * invk;
    float ex0 = ss0 * invk, ex1 = ss1 * invk, ex2 = ss2 * invk;
    float st0 = sqrtf(fmaxf(ex0 - mu0 * mu0, 0.f));
    float st1 = sqrtf(fmaxf(ex1 - mu1 * mu1, 0.f));
    float st2 = sqrtf(fmaxf(ex2 - mu2 * mu2, 0.f));
    float nrm = sqrtf(mu0 * mu0 + mu1 * mu1 + mu2 * mu2) + 1e-8f;
    float u0 = mu0 / nrm, u1 = mu1 / nrm, u2 = mu2 / nrm;
    float cr0 = qy * u2 - qz * u1;
    float cr1 = qz * u0 - qx * u2;
    float cr2 = qx * u1 - qy * u0;
    float mq0 = fmaxf(mx0 * mx0, mn0 * mn0);
    float mq1 = fmaxf(mx1 * mx1, mn1 * mn1);
    float mq2 = fmaxf(mx2 * mx2, mn2 * mn2);

    float f[CH] = { qx, qy, qz,
                    mu0, mu1, mu2,
                    mx0, mx1, mx2,
                    mn0, mn1, mn2,
                    st0, st1, st2,
                    qx - mu0, qy - mu1, qz - mu2,
                    u0, u1, u2,
                    cr0, cr1, cr2,
                    mq0, mq1, mq2,
                    ex0, ex1, ex2 };

#pragma unroll
    for (int c = 0; c < CH; ++c) {
        float v = f[c];
#pragma unroll
        for (int off = 32; off >= 1; off >>= 1)
            v = fmaxf(v, __shfl_xor(v, off, 64));
        if (l == 0)
            atomicMax(pool + b * CH + c, enc_f32(v));
    }
}

__global__ void final_mm_kernel(const unsigned* __restrict__ pool,
                                const float* __restrict__ W,
                                const float* __restrict__ bias,
                                float* __restrict__ out) {
    int t = blockIdx.x * blockDim.x + threadIdx.x;
    if (t >= BATCH * 32) return;
    int bb = t >> 5, e = t & 31;
    float acc = bias[e];
#pragma unroll
    for (int c = 0; c < CH; ++c)
        acc += dec_f32(pool[bb * CH + c]) * W[e * CH + c];
    out[bb * 32 + e] = acc;
}

extern "C" void kernel_launch(void* const* d_in, const int* in_sizes, int n_in,
                              void* d_out, int out_size, void* d_ws, size_t ws_size,
                              hipStream_t stream) {
    const float* x    = (const float*)d_in[0];   // [16, 4096, 3] f32
    const float* W    = (const float*)d_in[1];   // [32, 30] f32
    const float* bias = (const float*)d_in[2];   // [32] f32
    float*       out  = (float*)d_out;           // [16, 32] f32
    unsigned*    pool = (unsigned*)d_ws;         // [16, 30] encoded f32

    // planes 48K + t8 1K + cnt 1K + fifo 28K = 78 KB -> 2 blocks/CU
    const size_t lds_bytes = (size_t)(3 * NPTS + 2 * NW * 64) * sizeof(float)
                           + (size_t)(NW * FD * 64) * sizeof(unsigned short);

    hipLaunchKernelGGL(init_pool_kernel, dim3(1), dim3(512), 0, stream, pool);
    hipLaunchKernelGGL(knn_feat_kernel, dim3(BATCH * (NPTS / 64)), dim3(256),
                       lds_bytes, stream, x, pool);
    hipLaunchKernelGGL(final_mm_kernel, dim3(1), dim3(512), 0, stream, pool, W, bias, out);
}

// Round 6
// 273.996 us; speedup vs baseline: 2.2482x; 1.1352x over previous
//
#include <hip/hip_runtime.h>

#pragma clang fp contract(off)

#define BATCH 16
#define NPTS  4096
#define KNN   32
#define NW    4                 // waves per block = candidate-chunk split factor
#define CHUNK (NPTS / NW)       // 1024 candidates per wave
#define CH    30
#define Q8    8                 // per-chunk list depth (union 4*8 = 32 -> t_cap bound)
#define FD    42                // per-(wave,lane) index-FIFO depth (u16 entries)

#define INF_F __builtin_inff()

// Order-preserving float->uint encoding for atomic max (handles negatives).
__device__ __forceinline__ unsigned enc_f32(float f) {
    unsigned u = __float_as_uint(f);
    return (u & 0x80000000u) ? ~u : (u | 0x80000000u);
}
__device__ __forceinline__ float dec_f32(unsigned e) {
    unsigned u = (e & 0x80000000u) ? (e & 0x7FFFFFFFu) : ~e;
    return __uint_as_float(u);
}

__device__ __forceinline__ float med3f(float a, float b, float c) {
#if __has_builtin(__builtin_amdgcn_fmed3f)
    return __builtin_amdgcn_fmed3f(a, b, c);
#else
    float r;
    asm("v_med3_f32 %0, %1, %2, %3" : "=v"(r) : "v"(a), "v"(b), "v"(c));
    return r;
#endif
}

// |p|^2 — ONE formula, used for the pw plane and qw alike.
__device__ __forceinline__ float sq3(float px, float py, float pz) {
    return __builtin_fmaf(px, px, __builtin_fmaf(py, py, pz * pz));
}
// Distance with precomputed pw: 5 VALU. Same expression in EVERY pass ->
// bit-identical d everywhere (explicit fma, immune to contraction).
__device__ __forceinline__ float distp(float qx, float qy, float qz, float qw,
                                       float px, float py, float pz, float pw) {
    float dt = __builtin_fmaf(qx, px, __builtin_fmaf(qy, py, qz * pz));
    return __builtin_fmaf(-2.0f, dt, qw + pw);
}

__global__ void init_pool_kernel(unsigned* __restrict__ pool) {
    int i = blockIdx.x * blockDim.x + threadIdx.x;
    if (i < BATCH * CH) pool[i] = 0u;   // 0 is below every encoded finite float
}

// Block: 256 threads = 4 waves. Lane l owns query (qg*64 + l); wave w scans
// candidate chunk [w*1024, w*1024+1024). Candidate xyz read straight from
// global (wave-uniform address -> single broadcast L2 line); |p|^2 from a
// per-block LDS plane. LDS total ~39 KB -> 4 blocks/CU.
__launch_bounds__(256, 4)
__global__ void knn_feat_kernel(const float* __restrict__ x,
                                unsigned* __restrict__ pool) {
    __shared__ float          pw_lds[NPTS];        // 16 KB
    __shared__ float          t8[NW * 64];         // 1 KB
    __shared__ unsigned short fifo[NW * FD * 64];  // 21.5 KB
    __shared__ unsigned char  cbs[NW * 64];        // 256 B

    const int b   = blockIdx.x >> 6;               // 64 query-groups per batch
    const int qg  = blockIdx.x & 63;
    const int tid = threadIdx.x;
    const int w   = tid >> 6;                      // wave id = chunk id
    const int l   = tid & 63;                      // lane = query slot
    const int q   = qg * 64 + l;
    const float* __restrict__ xb = x + (size_t)b * NPTS * 3;

    // Stage |p|^2 plane (deterministic same bits in every block).
    for (int i = tid; i < NPTS; i += 256)
        pw_lds[i] = sq3(xb[i * 3 + 0], xb[i * 3 + 1], xb[i * 3 + 2]);
    __syncthreads();

    const float qx = xb[q * 3 + 0], qy = xb[q * 3 + 1], qz = xb[q * 3 + 2];
    const float qw = pw_lds[q];                    // same bits as candidates' pw

    const float4* __restrict__ g4  = (const float4*)xb + (size_t)w * (CHUNK * 3 / 4);
    const float4* __restrict__ pw4 = (const float4*)pw_lds + (size_t)w * (CHUNK / 4);

    // ---- Pass 1: top-8 distance VALUES of my chunk (sorted asc). ----
    float arr[Q8];
#pragma unroll
    for (int j = 0; j < Q8; ++j) arr[j] = INF_F;

#define INSERT8(dv)                                            \
    {                                                          \
        _Pragma("unroll")                                      \
        for (int j = Q8 - 1; j >= 1; --j)                      \
            arr[j] = med3f(arr[j - 1], arr[j], (dv));          \
        arr[0] = fminf(arr[0], (dv));                          \
    }

    for (int m4 = 0; m4 < CHUNK / 4; ++m4) {
        float4 A = g4[3 * m4], B = g4[3 * m4 + 1], C = g4[3 * m4 + 2];
        float4 PW = pw4[m4];
        float d0 = distp(qx, qy, qz, qw, A.x, A.y, A.z, PW.x);
        float d1 = distp(qx, qy, qz, qw, A.w, B.x, B.y, PW.y);
        float d2 = distp(qx, qy, qz, qw, B.z, B.w, C.x, PW.z);
        float d3 = distp(qx, qy, qz, qw, C.y, C.z, C.w, PW.w);
        INSERT8(d0); INSERT8(d1); INSERT8(d2); INSERT8(d3);
    }
#undef INSERT8

    t8[w * 64 + l] = arr[Q8 - 1];
    __syncthreads();

    // t_cap >= true 32nd distance: union of 4 chunk-top-8s = 32 distinct points.
    const float t_cap = fmaxf(fmaxf(t8[0 * 64 + l], t8[1 * 64 + l]),
                              fmaxf(t8[2 * 64 + l], t8[3 * 64 + l]));

    // ---- Pass 2: collect chunk-local indices with d <= t_cap. ----
    unsigned short* __restrict__ fw = fifo + (w * FD) * 64 + l;
    int cnt = 0;
    for (int m4 = 0; m4 < CHUNK / 4; ++m4) {
        float4 A = g4[3 * m4], B = g4[3 * m4 + 1], C = g4[3 * m4 + 2];
        float4 PW = pw4[m4];
        float d0 = distp(qx, qy, qz, qw, A.x, A.y, A.z, PW.x);
        float d1 = distp(qx, qy, qz, qw, A.w, B.x, B.y, PW.y);
        float d2 = distp(qx, qy, qz, qw, B.z, B.w, C.x, PW.z);
        float d3 = distp(qx, qy, qz, qw, C.y, C.z, C.w, PW.w);
        int mb = m4 * 4;
        if (__any(d0 <= t_cap)) {
            if (d0 <= t_cap && cnt < FD) { fw[cnt * 64] = (unsigned short)(mb + 0); ++cnt; }
        }
        if (__any(d1 <= t_cap)) {
            if (d1 <= t_cap && cnt < FD) { fw[cnt * 64] = (unsigned short)(mb + 1); ++cnt; }
        }
        if (__any(d2 <= t_cap)) {
            if (d2 <= t_cap && cnt < FD) { fw[cnt * 64] = (unsigned short)(mb + 2); ++cnt; }
        }
        if (__any(d3 <= t_cap)) {
            if (d3 <= t_cap && cnt < FD) { fw[cnt * 64] = (unsigned short)(mb + 3); ++cnt; }
        }
    }
    cbs[w * 64 + l] = (unsigned char)cnt;
    __syncthreads();

    if (w != 0) return;   // no barriers past this point

    // ---- Phase 3 (wave 0): exact selection + stats over collected entries. ----
    const int c0 = cbs[0 * 64 + l], c1 = cbs[1 * 64 + l],
              c2 = cbs[2 * 64 + l], c3 = cbs[3 * 64 + l];

    float a32[KNN];
#pragma unroll
    for (int j = 0; j < KNN; ++j) a32[j] = INF_F;

#pragma unroll
    for (int ww = 0; ww < NW; ++ww) {
        const int c = (ww == 0) ? c0 : (ww == 1) ? c1 : (ww == 2) ? c2 : c3;
        for (int i = 0; i < c; ++i) {
            int idx = (int)fifo[((ww * FD + i) * 64) + l] + ww * CHUNK;
            const float* pp = xb + 3 * idx;
            float d = distp(qx, qy, qz, qw, pp[0], pp[1], pp[2], pw_lds[idx]);
#pragma unroll
            for (int j = KNN - 1; j >= 1; --j)
                a32[j] = med3f(a32[j - 1], a32[j], d);
            a32[0] = fminf(a32[0], d);
        }
    }
    const float thr = a32[KNN - 1];
    int c_lt = 0;
#pragma unroll
    for (int j = 0; j < KNN; ++j) c_lt += a32[j] < thr;
    const int need = KNN - c_lt;                   // ties to take, in index order

    float s0 = 0.f, s1 = 0.f, s2 = 0.f;
    float ss0 = 0.f, ss1 = 0.f, ss2 = 0.f;
    float mx0 = -INF_F, mx1 = -INF_F, mx2 = -INF_F;
    float mn0 =  INF_F, mn1 =  INF_F, mn2 =  INF_F;
    int eq_seen = 0;
#pragma unroll
    for (int ww = 0; ww < NW; ++ww) {              // (ww asc, i asc) = index order
        const int c = (ww == 0) ? c0 : (ww == 1) ? c1 : (ww == 2) ? c2 : c3;
        for (int i = 0; i < c; ++i) {
            int idx = (int)fifo[((ww * FD + i) * 64) + l] + ww * CHUNK;
            const float* pp = xb + 3 * idx;
            float px = pp[0], py = pp[1], pz = pp[2];
            float d = distp(qx, qy, qz, qw, px, py, pz, pw_lds[idx]);
            bool is_eq = (d == thr);
            bool take = (d < thr) || (is_eq && eq_seen < need);
            eq_seen += is_eq ? 1 : 0;
            if (take) {
                float r0 = px - qx, r1 = py - qy, r2 = pz - qz;
                s0 += r0;  s1 += r1;  s2 += r2;
                ss0 += r0 * r0;  ss1 += r1 * r1;  ss2 += r2 * r2;
                mx0 = fmaxf(mx0, r0); mx1 = fmaxf(mx1, r1); mx2 = fmaxf(mx2, r2);
                mn0 = fminf(mn0, r0); mn1 = fminf(mn1, r1); mn2 = fminf(mn2, r2);
            }
        }
    }

    const float invk = 1.0f / (float)KNN;
    float mu0 = s0 * invk, mu1 = s1 * invk, mu2 = s2 * invk;
    float ex0 = ss0 * invk, ex1 = ss1 * invk, ex2 = ss2 * invk;
    float st0 = sqrtf(fmaxf(ex0 - mu0 * mu0, 0.f));
    float st1 = sqrtf(fmaxf(ex1 - mu1 * mu1, 0.f));
    float st2 = sqrtf(fmaxf(ex2 - mu2 * mu2, 0.f));
    float nrm = sqrtf(mu0 * mu0 + mu1 * mu1 + mu2 * mu2) + 1e-8f;
    float u0 = mu0 / nrm, u1 = mu1 / nrm, u2 = mu2 / nrm;
    float cr0 = qy * u2 - qz * u1;
    float cr1 = qz * u0 - qx * u2;
    float cr2 = qx * u1 - qy * u0;
    float mq0 = fmaxf(mx0 * mx0, mn0 * mn0);
    float mq1 = fmaxf(mx1 * mx1, mn1 * mn1);
    float mq2 = fmaxf(mx2 * mx2, mn2 * mn2);

    float f[CH] = { qx, qy, qz,
                    mu0, mu1, mu2,
                    mx0, mx1, mx2,
                    mn0, mn1, mn2,
                    st0, st1, st2,
                    qx - mu0, qy - mu1, qz - mu2,
                    u0, u1, u2,
                    cr0, cr1, cr2,
                    mq0, mq1, mq2,
                    ex0, ex1, ex2 };

#pragma unroll
    for (int c = 0; c < CH; ++c) {
        float v = f[c];
#pragma unroll
        for (int off = 32; off >= 1; off >>= 1)
            v = fmaxf(v, __shfl_xor(v, off, 64));
        if (l == 0)
            atomicMax(pool + b * CH + c, enc_f32(v));
    }
}

__global__ void final_mm_kernel(const unsigned* __restrict__ pool,
                                const float* __restrict__ W,
                                const float* __restrict__ bias,
                                float* __restrict__ out) {
    int t = blockIdx.x * blockDim.x + threadIdx.x;
    if (t >= BATCH * 32) return;
    int bb = t >> 5, e = t & 31;
    float acc = bias[e];
#pragma unroll
    for (int c = 0; c < CH; ++c)
        acc += dec_f32(pool[bb * CH + c]) * W[e * CH + c];
    out[bb * 32 + e] = acc;
}

extern "C" void kernel_launch(void* const* d_in, const int* in_sizes, int n_in,
                              void* d_out, int out_size, void* d_ws, size_t ws_size,
                              hipStream_t stream) {
    const float* x    = (const float*)d_in[0];   // [16, 4096, 3] f32
    const float* W    = (const float*)d_in[1];   // [32, 30] f32
    const float* bias = (const float*)d_in[2];   // [32] f32
    float*       out  = (float*)d_out;           // [16, 32] f32
    unsigned*    pool = (unsigned*)d_ws;         // [16, 30] encoded f32

    hipLaunchKernelGGL(init_pool_kernel, dim3(1), dim3(512), 0, stream, pool);
    hipLaunchKernelGGL(knn_feat_kernel, dim3(BATCH * (NPTS / 64)), dim3(256),
                       0, stream, x, pool);
    hipLaunchKernelGGL(final_mm_kernel, dim3(1), dim3(512), 0, stream, pool, W, bias, out);
}